// Round 13
// baseline (247.801 us; speedup 1.0000x reference)
//
#include <hip/hip_runtime.h>
#include <hip/hip_bf16.h>

#define NB 32
#define NS 4
#define NL 64
#define NC 32
#define NH 4
#define ND 8
#define NCP 16

using fp = const float* __restrict__;

// ---------------------------------------------------------------------------
// KALL: one launch. Block = (b, it) -> 32*8 = 256 blocks, 256 threads,
// t = w*64 + l (wave w = track, lane l = bin row). 80 KB LDS arena:
//   A[8192]    : ks [s][e][l]  ->  xs [s][c][l]  ->  ppws (32 KB staging)
//   V[8192]    : vs [s][e][l]  ->  mh [c][l] (0:2048) + u (2048:6144)
//                                  + invn (6144:6208)
//   bulk_s     : [l][m^  (l&31)] XOR-swizzled (write & read conflict-free)
// Each block redoes batch b's full attention (8x redundant, ~5 us chip-wide
// VALU) then computes its own 8-i tile of the pair stage. No workspace.
// ---------------------------------------------------------------------------
__global__ __launch_bounds__(256, 2) void kall(
    fp ctcf, fp hac, fp me1, fp me3, fp bulk,
    fp we_w, fp we_b, fp pos, fp mn_g, fp mn_b,
    fp wq, fp bq, fp wk, fp bk, fp wv, fp bv,
    fp wo, fp bo, fp an_g, fp an_b,
    fp conv_w, fp conv_b, fp gate_w, fp gate_b,
    fp pp_w, fp pp_b, fp ada_g, fp ada_b, fp ada_alpha,
    float* __restrict__ out)
{
    __shared__ float A[8192];        // 32 KB
    __shared__ float V[8192];        // 32 KB
    __shared__ float bulk_s[4096];   // 16 KB, XOR-swizzled

    const int t  = threadIdx.x;
    const int w  = t >> 6;     // track (phase 1-2), reused later
    const int l  = t & 63;     // bin row / j lane
    const int b  = blockIdx.x >> 3;
    const int it = blockIdx.x & 7;

    // ---- stage bulk[b], swizzled: bulk_s[row*64 + (col^(row&31))] ----
#pragma unroll
    for (int k = 0; k < 16; k++){
        int idx = k*256 + t;
        int row = idx >> 6, col = idx & 63;
        bulk_s[row*64 + (col ^ (row & 31))] = bulk[b*4096 + idx];
    }

    // ---- embed + LN (track w, row l) ----
    fp sigp = (w == 0) ? ctcf : (w == 1) ? hac : (w == 2) ? me1 : me3;
    const float sig = sigp[b*NL + l];
    float x[NC];
    float mean = 0.f;
#pragma unroll
    for (int c = 0; c < NC; c++){
        x[c] = sig * we_w[c] + we_b[c] + pos[l*NC + c];
        mean += x[c];
    }
    mean *= (1.f/NC);
    float var = 0.f;
#pragma unroll
    for (int c = 0; c < NC; c++){ float d = x[c] - mean; var += d*d; }
    var *= (1.f/NC);
    float inv = rsqrtf(var + 1e-5f);
#pragma unroll
    for (int c = 0; c < NC; c++) x[c] = (x[c] - mean)*inv*mn_g[c] + mn_b[c];

    // ---- full Q row (regs) + K,V rows -> LDS [s][e][l] ----
    float q[NC];
#pragma unroll
    for (int e = 0; e < NC; e++){
        float aq = bq[e], ak = bk[e], av = bv[e];
#pragma unroll
        for (int c = 0; c < NC; c++){
            float xv = x[c];
            aq += xv * wq[e*NC + c];
            ak += xv * wk[e*NC + c];
            av += xv * wv[e*NC + c];
        }
        q[e] = aq;
        A[w*2048 + e*64 + l] = ak;   // stride-1
        V[w*2048 + e*64 + l] = av;
    }
    __syncthreads();

    // ---- attention: all 4 heads for (track w, row l) ----
    const float rs8 = 0.35355339059327373f;
    float ao[NC];
    for (int h = 0; h < NH; h++){
        const float cw = conv_w[h], cb = conv_b[h];
        float srow[NL];
        float mx = -1e30f;
        for (int m = 0; m < NL; m++){
            float dot = 0.f;
#pragma unroll
            for (int d = 0; d < ND; d++)
                dot += q[h*ND + d] * A[w*2048 + (h*ND + d)*64 + m];  // broadcast
            float v = dot*rs8 + bulk_s[l*64 + (m ^ (l & 31))]*cw + cb;
            srow[m] = v;
            mx = fmaxf(mx, v);
        }
        float sm = 0.f;
        for (int m = 0; m < NL; m++){ srow[m] = __expf(srow[m] - mx); sm += srow[m]; }
        float is = 1.f / sm;
        float o[ND];
#pragma unroll
        for (int d = 0; d < ND; d++) o[d] = 0.f;
        for (int m = 0; m < NL; m++){
            float a = srow[m] * is;
#pragma unroll
            for (int d = 0; d < ND; d++)
                o[d] += a * V[w*2048 + (h*ND + d)*64 + m];           // broadcast
        }
#pragma unroll
        for (int c8 = 0; c8 < ND; c8++){
            float g = gate_b[h*ND + c8];
#pragma unroll
            for (int d = 0; d < ND; d++) g += gate_w[(h*ND + c8)*ND + d] * o[d];
            ao[h*ND + c8] = o[c8] * (1.f/(1.f + __expf(-g)));
        }
    }
    __syncthreads();   // all ks/vs reads done

    // ---- out-proj + residual + LN (serial per thread) -> xs in A ----
    {
        float xp[NC];
        float mn2 = 0.f;
#pragma unroll
        for (int c = 0; c < NC; c++){
            float a = bo[c];
#pragma unroll
            for (int e = 0; e < NC; e++) a += ao[e] * wo[c*NC + e];
            float val = x[c] + a;
            xp[c] = val; mn2 += val;
        }
        mn2 *= (1.f/NC);
        float vr = 0.f;
#pragma unroll
        for (int c = 0; c < NC; c++){ float d = xp[c] - mn2; vr += d*d; }
        vr *= (1.f/NC);
        float iv = rsqrtf(vr + 1e-5f);
#pragma unroll
        for (int c = 0; c < NC; c++)
            A[w*2048 + c*64 + l] = (xp[c] - mn2)*iv*an_g[c] + an_b[c];
    }
    __syncthreads();

    // ---- max over tracks -> mh raw in V[0:2048] ----
#pragma unroll
    for (int k = 0; k < 8; k++){
        int cl = k*256 + t;
        float v = A[cl];
        v = fmaxf(v, A[2048 + cl]);
        v = fmaxf(v, A[4096 + cl]);
        v = fmaxf(v, A[6144 + cl]);
        V[cl] = v;
    }
    __syncthreads();
    if (t < NL){
        float sq = 0.f;
#pragma unroll
        for (int c = 0; c < NC; c++){ float v = V[c*64 + t]; sq += v*v; }
        V[6144 + t] = 1.f / fmaxf(sqrtf(sq), 1e-3f);
    }
    __syncthreads();
#pragma unroll
    for (int k = 0; k < 8; k++){
        int cl = k*256 + t;
        V[cl] *= V[6144 + (cl & 63)];
    }
    __syncthreads();

    // ---- stage pp_w pass 0 (p=0..7) into A ----
    {
        const float4* src = (const float4*)(pp_w);
        float4* dst = (float4*)A;
#pragma unroll
        for (int k = 0; k < 8; k++) dst[k*256 + t] = src[k*256 + t];
    }
    __syncthreads();

    // ---- u pass 0: u[p][ip][d] = sum_c mh[c][it*8+ip]*ppws[p][c][d] ----
#pragma unroll
    for (int k = 0; k < 8; k++){
        int idx = k*256 + t;               // 0..2047
        int d  = idx & 31;
        int ip = (idx >> 5) & 7;
        int pl = idx >> 8;                 // wave-uniform per k
        float acc = 0.f;
#pragma unroll
        for (int c = 0; c < NC; c++)
            acc += V[c*64 + it*8 + ip] * A[pl*1024 + c*32 + d];
        V[2048 + pl*256 + ip*32 + d] = acc;
    }
    __syncthreads();

    // ---- stage pp_w pass 1 (p=8..15) ----
    {
        const float4* src = (const float4*)(pp_w + 8*NC*NC);
        float4* dst = (float4*)A;
#pragma unroll
        for (int k = 0; k < 8; k++) dst[k*256 + t] = src[k*256 + t];
    }
    __syncthreads();

    // ---- u pass 1 ----
#pragma unroll
    for (int k = 0; k < 8; k++){
        int idx = k*256 + t;
        int d  = idx & 31;
        int ip = (idx >> 5) & 7;
        int pl = idx >> 8;
        float acc = 0.f;
#pragma unroll
        for (int c = 0; c < NC; c++)
            acc += V[c*64 + it*8 + ip] * A[pl*1024 + c*32 + d];
        V[4096 + pl*256 + ip*32 + d] = acc;
    }
    __syncthreads();

    // ---- Step C/D: 2 i-rows per thread (ip = w, w+4); lane j = l ----
    const int j = l;
    float md[NC];
#pragma unroll
    for (int c = 0; c < NC; c++) md[c] = V[c*64 + j];   // stride-1

    const float alpha = ada_alpha[0];
#pragma unroll
    for (int rep = 0; rep < 2; rep++){
        const int ip = w + 4*rep;          // 0..7, wave-uniform
        const int i  = it*8 + ip;
        float f[NCP];
        float fsum = 0.f, fsq = 0.f;
#pragma unroll
        for (int p = 0; p < NCP; p++){
            float a = 0.f;
#pragma unroll
            for (int d = 0; d < NC; d++)
                a += V[2048 + p*256 + ip*32 + d] * md[d];   // broadcast
            a += pp_b[p];
            f[p] = a; fsum += a; fsq += a*a;
        }
        float fmean = fsum * (1.f/NCP);
        float fvar  = fsq * (1.f/NCP) - fmean*fmean;
        float finv  = rsqrtf(fvar + 1e-5f);
#pragma unroll
        for (int p = 0; p < NCP; p++){
            float v = f[p] + alpha * ((f[p] - fmean)*finv*ada_g[p] + ada_b[p]);
            out[((b*NCP + p)*NL + i)*NL + j] = v / (1.f + __expf(-v));
        }
    }
}

extern "C" void kernel_launch(void* const* d_in, const int* in_sizes, int n_in,
                              void* d_out, int out_size, void* d_ws, size_t ws_size,
                              hipStream_t stream)
{
    kall<<<NB*8, 256, 0, stream>>>(
        (fp)d_in[0], (fp)d_in[1], (fp)d_in[2], (fp)d_in[3], (fp)d_in[4],
        (fp)d_in[5], (fp)d_in[6], (fp)d_in[7], (fp)d_in[8], (fp)d_in[9],
        (fp)d_in[10], (fp)d_in[11], (fp)d_in[12], (fp)d_in[13], (fp)d_in[14], (fp)d_in[15],
        (fp)d_in[16], (fp)d_in[17], (fp)d_in[18], (fp)d_in[19],
        (fp)d_in[20], (fp)d_in[21], (fp)d_in[22], (fp)d_in[23],
        (fp)d_in[24], (fp)d_in[25], (fp)d_in[26], (fp)d_in[27], (fp)d_in[28],
        (float*)d_out);
}

// Round 14
// 143.230 us; speedup vs baseline: 1.7301x; 1.7301x over previous
//
#include <hip/hip_runtime.h>
#include <hip/hip_bf16.h>

#define NB 32
#define NS 4
#define NL 64
#define NC 32
#define NH 4
#define ND 8
#define NCP 16

using fp = const float* __restrict__;

// ---------------------------------------------------------------------------
// K1 v3 (R12 champion): block=(b,s,half) -> 256 blocks, 256 threads = 4 waves.
// Phase 1 (t = w*64+l): embed+LN row l; Q/K/V slice e in [8w,8w+8) -> LDS
//   qs/ks/vs [e][l]; x slice -> xs [e][l].
// Phase 2: wave w = head w; 2 lanes per row: r = half*32 + (lane>>1),
//   m-range = (lane&1)*32 .. +32; combine via __shfl_xor(.,1).
// Phase 3: out-proj 4 channels/thread, LN via LDS reduce; write xpostT
//   [b][s][c][l] coalesced. All LDS patterns broadcast / 2-way (free).
// ---------------------------------------------------------------------------
__global__ __launch_bounds__(256) void k1_attn(
    fp ctcf, fp hac, fp me1, fp me3, fp bulk,
    fp we_w, fp we_b, fp pos, fp mn_g, fp mn_b,
    fp wq, fp bq, fp wk, fp bk, fp wv, fp bv,
    fp wo, fp bo, fp an_g, fp an_b,
    fp conv_w, fp conv_b, fp gate_w, fp gate_b,
    float* __restrict__ xpostT)
{
    __shared__ float qs_s[NC*NL];      // [e][l]
    __shared__ float ks_s[NC*NL];      // [e][l]
    __shared__ float vs_s[NC*NL];      // [e][l]
    __shared__ float xs_s[NC*NL];      // [e][l]
    __shared__ float ao_s[NC*NL];      // [e][r]
    __shared__ float bulk_s[32*65];    // [lr][m], rows of this half, padded
    __shared__ float red1[32*8], red2[32*8];
    __shared__ float mstat[32], istat[32];

    const int t    = threadIdx.x;
    const int w    = t >> 6;
    const int l    = t & 63;
    const int bx   = blockIdx.x;
    const int b    = bx >> 3;
    const int s    = (bx >> 1) & 3;
    const int half = bx & 1;

    for (int idx = t; idx < 32*NL; idx += 256){
        int lr = idx >> 6, m = idx & 63;
        bulk_s[lr*65 + m] = bulk[b*NL*NL + (half*32 + lr)*NL + m];
    }

    fp sigp = (s == 0) ? ctcf : (s == 1) ? hac : (s == 2) ? me1 : me3;
    const float sig = sigp[b*NL + l];

    // ---- phase 1: embed + LN + QKV slice for row l ----
    float x[NC];
    float mean = 0.f;
#pragma unroll
    for (int c = 0; c < NC; c++){
        x[c] = sig * we_w[c] + we_b[c] + pos[l*NC + c];
        mean += x[c];
    }
    mean *= (1.f/NC);
    float var = 0.f;
#pragma unroll
    for (int c = 0; c < NC; c++){ float d = x[c] - mean; var += d*d; }
    var *= (1.f/NC);
    float inv = rsqrtf(var + 1e-5f);
#pragma unroll
    for (int c = 0; c < NC; c++) x[c] = (x[c] - mean)*inv*mn_g[c] + mn_b[c];

#pragma unroll
    for (int e8 = 0; e8 < ND; e8++){
        int e = w*ND + e8;
        float aq = bq[e], ak = bk[e], av = bv[e];
#pragma unroll
        for (int c = 0; c < NC; c++){
            float xv = x[c];
            aq += xv * wq[e*NC + c];
            ak += xv * wk[e*NC + c];
            av += xv * wv[e*NC + c];
        }
        qs_s[e*NL + l] = aq;
        ks_s[e*NL + l] = ak;
        vs_s[e*NL + l] = av;
        xs_s[e*NL + l] = x[e];
    }
    __syncthreads();

    // ---- phase 2: attention, head w, 2 lanes per row ----
    const int rl  = l >> 1;
    const int r   = half*32 + rl;
    const int mh_ = l & 1;
    const int m0  = mh_*32;

    float q8[ND];
#pragma unroll
    for (int d = 0; d < ND; d++) q8[d] = qs_s[(w*ND + d)*NL + r];

    const float rs8 = 0.35355339059327373f;
    const float cw = conv_w[w], cb = conv_b[w];
    float srow[32];
    float mx = -1e30f;
    for (int mi = 0; mi < 32; mi++){
        int m = m0 + mi;
        float dot = 0.f;
#pragma unroll
        for (int d = 0; d < ND; d++)
            dot += q8[d] * ks_s[(w*ND + d)*NL + m];
        float v = dot*rs8 + bulk_s[rl*65 + m]*cw + cb;
        srow[mi] = v;
        mx = fmaxf(mx, v);
    }
    mx = fmaxf(mx, __shfl_xor(mx, 1));
    float sm = 0.f;
    for (int mi = 0; mi < 32; mi++){ srow[mi] = __expf(srow[mi] - mx); sm += srow[mi]; }
    sm += __shfl_xor(sm, 1);
    float is = 1.f / sm;

    float o[ND];
#pragma unroll
    for (int d = 0; d < ND; d++) o[d] = 0.f;
    for (int mi = 0; mi < 32; mi++){
        float a = srow[mi] * is;
#pragma unroll
        for (int d = 0; d < ND; d++)
            o[d] += a * vs_s[(w*ND + d)*NL + m0 + mi];
    }
#pragma unroll
    for (int d = 0; d < ND; d++) o[d] += __shfl_xor(o[d], 1);

#pragma unroll
    for (int k = 0; k < 4; k++){
        int c8 = mh_*4 + k;
        float g = gate_b[w*ND + c8];
#pragma unroll
        for (int d = 0; d < ND; d++) g += gate_w[(w*ND + c8)*ND + d] * o[d];
        ao_s[(w*ND + c8)*NL + r] = o[c8] * (1.f/(1.f + __expf(-g)));
    }
    __syncthreads();

    // ---- phase 3: out-proj (4 channels/thread) + residual + LN ----
    const int r3  = t & 31;
    const int rg  = half*32 + r3;
    const int cg  = t >> 5;
    float vals[4];
    float psum = 0.f, psq = 0.f;
#pragma unroll
    for (int k = 0; k < 4; k++){
        int c = cg*4 + k;
        float a = bo[c];
#pragma unroll
        for (int e = 0; e < NC; e++) a += ao_s[e*NL + rg] * wo[c*NC + e];
        float val = xs_s[c*NL + rg] + a;
        vals[k] = val; psum += val; psq += val*val;
    }
    red1[r3*8 + cg] = psum;
    red2[r3*8 + cg] = psq;
    __syncthreads();
    if (t < 32){
        float sum = 0.f, ssq = 0.f;
#pragma unroll
        for (int g = 0; g < 8; g++){ sum += red1[t*8 + g]; ssq += red2[t*8 + g]; }
        float mn = sum * (1.f/NC);
        float vr = ssq * (1.f/NC) - mn*mn;
        mstat[t] = mn;
        istat[t] = rsqrtf(vr + 1e-5f);
    }
    __syncthreads();
    {
        float mn = mstat[r3], iv = istat[r3];
#pragma unroll
        for (int k = 0; k < 4; k++){
            int c = cg*4 + k;
            xpostT[((b*NS + s)*NC + c)*NL + rg] = (vals[k] - mn)*iv*an_g[c] + an_b[c];
        }
    }
}

// ---------------------------------------------------------------------------
// K23 v2 (R12 champion): block=(b,it) -> 512 blocks, 256 threads, 48 KB LDS.
// pp_w staged to LDS in two 32 KB passes; mhat cooperative; all global
// reads coalesced; LDS patterns conflict-free.
// ---------------------------------------------------------------------------
__global__ __launch_bounds__(256) void k23_pair(
    const float* __restrict__ xpostT, fp pp_w,
    fp pp_b, fp ada_g, fp ada_b, fp ada_alpha,
    float* __restrict__ out)
{
    __shared__ float ppws[8*NC*NC];   // 8192 floats, 32 KB (per pass)
    __shared__ float mh[NC*NL];       // 2048 floats
    __shared__ float u[NCP*4*NC];     // 2048 floats ([0..63] = invn early)

    const int b  = blockIdx.x >> 4;
    const int it = blockIdx.x & 15;
    const int t  = threadIdx.x;
    const int w  = t >> 6;
    const int j  = t & 63;

    const float* xb = xpostT + b*NS*NC*NL;
#pragma unroll
    for (int k = 0; k < 8; k++){
        int cj = k*256 + t;
        float v = xb[cj];
        v = fmaxf(v, xb[NC*NL + cj]);
        v = fmaxf(v, xb[2*NC*NL + cj]);
        v = fmaxf(v, xb[3*NC*NL + cj]);
        mh[cj] = v;
    }
    __syncthreads();

    if (t < NL){
        float sq = 0.f;
#pragma unroll
        for (int c = 0; c < NC; c++){ float v = mh[c*NL + t]; sq += v*v; }
        u[t] = 1.f / fmaxf(sqrtf(sq), 1e-3f);
    }
    {
        const float4* src = (const float4*)(pp_w);
        float4* dst = (float4*)ppws;
#pragma unroll
        for (int k = 0; k < 8; k++) dst[k*256 + t] = src[k*256 + t];
    }
    __syncthreads();

#pragma unroll
    for (int k = 0; k < 8; k++){
        int cj = k*256 + t;
        mh[cj] *= u[cj & 63];
    }
    __syncthreads();

    float md[NC];
#pragma unroll
    for (int c = 0; c < NC; c++) md[c] = mh[c*NL + j];

#pragma unroll
    for (int loop = 0; loop < 4; loop++){
        int idx = loop*256 + t;
        int d  = idx & 31;
        int ip = (idx >> 5) & 3;
        int pl = idx >> 7;
        int i  = it*4 + ip;
        float acc = 0.f;
#pragma unroll
        for (int c = 0; c < NC; c++)
            acc += mh[c*NL + i] * ppws[pl*1024 + c*32 + d];
        u[pl*128 + ip*32 + d] = acc;
    }
    __syncthreads();

    {
        const float4* src = (const float4*)(pp_w + 8*NC*NC);
        float4* dst = (float4*)ppws;
#pragma unroll
        for (int k = 0; k < 8; k++) dst[k*256 + t] = src[k*256 + t];
    }
    __syncthreads();

#pragma unroll
    for (int loop = 0; loop < 4; loop++){
        int idx = loop*256 + t;
        int d  = idx & 31;
        int ip = (idx >> 5) & 3;
        int pl = idx >> 7;
        int i  = it*4 + ip;
        float acc = 0.f;
#pragma unroll
        for (int c = 0; c < NC; c++)
            acc += mh[c*NL + i] * ppws[pl*1024 + c*32 + d];
        u[(8 + pl)*128 + ip*32 + d] = acc;
    }
    __syncthreads();

    float f[NCP];
#pragma unroll 1
    for (int p = 0; p < NCP; p++){
        float a = 0.f;
#pragma unroll
        for (int d = 0; d < NC; d++)
            a += u[p*128 + w*32 + d] * md[d];
        f[p] = a;
    }

    const float alpha = ada_alpha[0];
    float fsum = 0.f, fsq = 0.f;
#pragma unroll
    for (int p = 0; p < NCP; p++){
        float v = f[p] + pp_b[p];
        f[p] = v; fsum += v; fsq += v*v;
    }
    float fmean = fsum * (1.f/NCP);
    float fvar  = fsq * (1.f/NCP) - fmean*fmean;
    float finv  = rsqrtf(fvar + 1e-5f);
    const int i = it*4 + w;
#pragma unroll
    for (int p = 0; p < NCP; p++){
        float v = f[p] + alpha * ((f[p] - fmean)*finv*ada_g[p] + ada_b[p]);
        out[((b*NCP + p)*NL + i)*NL + j] = v / (1.f + __expf(-v));
    }
}

extern "C" void kernel_launch(void* const* d_in, const int* in_sizes, int n_in,
                              void* d_out, int out_size, void* d_ws, size_t ws_size,
                              hipStream_t stream)
{
    float* xpostT = (float*)d_ws;                    // 32*4*32*64 = 262144 f32

    k1_attn<<<NB*NS*2, 256, 0, stream>>>(
        (fp)d_in[0], (fp)d_in[1], (fp)d_in[2], (fp)d_in[3], (fp)d_in[4],
        (fp)d_in[5], (fp)d_in[6], (fp)d_in[7], (fp)d_in[8], (fp)d_in[9],
        (fp)d_in[10], (fp)d_in[11], (fp)d_in[12], (fp)d_in[13], (fp)d_in[14], (fp)d_in[15],
        (fp)d_in[16], (fp)d_in[17], (fp)d_in[18], (fp)d_in[19],
        (fp)d_in[20], (fp)d_in[21], (fp)d_in[22], (fp)d_in[23], xpostT);

    k23_pair<<<NB*16, 256, 0, stream>>>(
        xpostT, (fp)d_in[24], (fp)d_in[25], (fp)d_in[26], (fp)d_in[27], (fp)d_in[28],
        (float*)d_out);
}